// Round 1
// baseline (91.131 us; speedup 1.0000x reference)
//
#include <hip/hip_runtime.h>

typedef unsigned short u16;
typedef __attribute__((ext_vector_type(8))) short short8;
typedef __attribute__((ext_vector_type(4))) float f32x4;

typedef void gvoid_t __attribute__((address_space(1)));
typedef void lvoid_t __attribute__((address_space(3)));

// Problem constants
#define M_DIM 8192   // B*T
#define N_DIM 1024   // K codebook entries
#define K_DIM 512    // D

__device__ __forceinline__ void async_copy16(const void* g, void* l) {
  // lane i's 16B land at (wave-uniform l) + i*16 — LDS layout must match that order.
  __builtin_amdgcn_global_load_lds((gvoid_t*)g, (lvoid_t*)l, 16, 0, 0);
}

__device__ __forceinline__ unsigned bf16bits(float v) {
  union { float f; unsigned u; } c; c.f = v;
  return (c.u + 0x7FFFu + ((c.u >> 16) & 1u)) >> 16;  // RNE
}

// Pass 1: fp32 -> bf16 convert + per-row sum of squares, for x (8192 rows) and
// codebook (1024 rows). One wave per row, 8 floats per lane.
__global__ __launch_bounds__(256) void cvt_sq_kernel(
    const float* __restrict__ x, const float* __restrict__ cb,
    u16* __restrict__ xb, u16* __restrict__ cbb,
    float* __restrict__ xsq, float* __restrict__ csq) {
  int row = blockIdx.x * 4 + (threadIdx.x >> 6);
  int lane = threadIdx.x & 63;
  const float* src; u16* dst; float* sq;
  if (row < M_DIM) {
    src = x + (size_t)row * K_DIM; dst = xb + (size_t)row * K_DIM; sq = xsq + row;
  } else {
    int r = row - M_DIM;
    src = cb + (size_t)r * K_DIM; dst = cbb + (size_t)r * K_DIM; sq = csq + r;
  }
  const float4* s4 = (const float4*)src;
  float4 v0 = s4[lane * 2];
  float4 v1 = s4[lane * 2 + 1];
  float f[8] = {v0.x, v0.y, v0.z, v0.w, v1.x, v1.y, v1.z, v1.w};
  float s = 0.f;
  unsigned pk[4];
#pragma unroll
  for (int i = 0; i < 4; i++) {
    s += f[2 * i] * f[2 * i] + f[2 * i + 1] * f[2 * i + 1];
    pk[i] = bf16bits(f[2 * i]) | (bf16bits(f[2 * i + 1]) << 16);
  }
  ((uint4*)dst)[lane] = make_uint4(pk[0], pk[1], pk[2], pk[3]);
#pragma unroll
  for (int off = 32; off > 0; off >>= 1) s += __shfl_xor(s, off, 64);
  if (lane == 0) *sq = s;
}

// Pass 2: 128x128 MFMA GEMM (bf16, B^T layout) + distance epilogue.
// LDS tiles 128x64 bf16 for A and B, staged via global_load_lds width 16.
// XOR swizzle: chunk row r stores global k-chunk (p ^ (r&7)) at position p,
// so ds_read_b128 frag reads spread across banks (<=2-way conflict).
__global__ __launch_bounds__(256) void qgemm_kernel(
    const u16* __restrict__ A, const u16* __restrict__ B,
    const float* __restrict__ xsq, const float* __restrict__ csq,
    const float* __restrict__ prec, float* __restrict__ out) {
  __shared__ char lds[32768];  // A: [0,16K), B: [16K,32K); row stride 128 B
  const int tid = threadIdx.x;
  const int wave = tid >> 6, lane = tid & 63;
  const int m0 = blockIdx.y * 128, n0 = blockIdx.x * 128;
  const int wm = wave >> 1, wn = wave & 1;   // 2x2 wave grid, 64x64 per wave
  const int srow = lane >> 3;                 // row within 8-row staging chunk
  const int scol = ((lane & 7) ^ srow) * 8;   // swizzled k-element offset
  const int ml = lane & 15, q = lane >> 4;

  f32x4 acc[4][4] = {};

  for (int k0 = 0; k0 < K_DIM; k0 += 64) {
#pragma unroll
    for (int c = wave; c < 16; c += 4) {
      const u16* ga = A + (size_t)(m0 + c * 8 + srow) * K_DIM + (k0 + scol);
      async_copy16(ga, lds + c * 1024);
      const u16* gb = B + (size_t)(n0 + c * 8 + srow) * K_DIM + (k0 + scol);
      async_copy16(gb, lds + 16384 + c * 1024);
    }
    __syncthreads();  // drains vmcnt(0): staged tiles visible
#pragma unroll
    for (int kk = 0; kk < 2; kk++) {
      const int p = ((((kk << 2) | q) ^ (lane & 7)) << 4);  // swizzled byte col
      short8 a[4], b[4];
#pragma unroll
      for (int i = 0; i < 4; i++) {
        a[i] = *(const short8*)(lds + (wm * 64 + i * 16 + ml) * 128 + p);
        b[i] = *(const short8*)(lds + 16384 + (wn * 64 + i * 16 + ml) * 128 + p);
      }
#pragma unroll
      for (int i = 0; i < 4; i++)
#pragma unroll
        for (int j = 0; j < 4; j++)
          acc[i][j] = __builtin_amdgcn_mfma_f32_16x16x32_bf16(a[i], b[j], acc[i][j], 0, 0, 0);
    }
    __syncthreads();  // protect LDS before next staging round
  }

  // Epilogue: out = p * (2*xc - ||x||^2 - ||c||^2)
  // C/D layout: col = lane&15, row = (lane>>4)*4 + reg  [m89-verified]
  const float p = prec[0];
  float csv[4];
#pragma unroll
  for (int j = 0; j < 4; j++) csv[j] = csq[n0 + wn * 64 + j * 16 + ml];
#pragma unroll
  for (int i = 0; i < 4; i++) {
#pragma unroll
    for (int r = 0; r < 4; r++) {
      int row = m0 + wm * 64 + i * 16 + q * 4 + r;
      float xs = xsq[row];
      float* orow = out + (size_t)row * N_DIM + n0 + wn * 64 + ml;
#pragma unroll
      for (int j = 0; j < 4; j++)
        orow[j * 16] = p * (2.0f * acc[i][j][r] - xs - csv[j]);
    }
  }
}

extern "C" void kernel_launch(void* const* d_in, const int* in_sizes, int n_in,
                              void* d_out, int out_size, void* d_ws, size_t ws_size,
                              hipStream_t stream) {
  const float* x    = (const float*)d_in[0];   // [8,1024,512] fp32
  const float* cb   = (const float*)d_in[1];   // [1024,512] fp32
  const float* prec = (const float*)d_in[2];   // [1] fp32
  float* out = (float*)d_out;                  // [8,1024,1024] fp32

  char* ws = (char*)d_ws;
  u16*   xb  = (u16*)(ws);                      // 8 MiB bf16 x
  u16*   cbb = (u16*)(ws + 8388608);            // 1 MiB bf16 codebook
  float* xsq = (float*)(ws + 9437184);          // 32 KiB
  float* csq = (float*)(ws + 9469952);          // 4 KiB

  // (8192 + 1024) rows / 4 rows per block = 2304 blocks
  cvt_sq_kernel<<<2304, 256, 0, stream>>>(x, cb, xb, cbb, xsq, csq);
  // 8 n-tiles x 64 m-tiles = 512 blocks (2 per CU)
  qgemm_kernel<<<dim3(8, 64), 256, 0, stream>>>(xb, cbb, xsq, csq, prec, out);
}